// Round 5
// baseline (127.287 us; speedup 1.0000x reference)
//
#include <hip/hip_runtime.h>
#include <stdint.h>

#define N_BOX 1024
#define C_CLS 80
#define B_IMG 4
#define K_PER 100
#define K_TOT 300
#define NEGF  (-1e30f)
#define NCAND (C_CLS * K_PER)    // 8000 candidates per image
#define M_SEL 8192               // flat-index packing base for final top-k
#define KPAD  1088               // 1024 + 64 swizzle pad

// workspace layout (bytes) — proven offsets; done_cnt claims bytes [0,16)
#define OFF_DONE    0            // int[4] per-image completion counters
#define OFF_WSCORE  1835008     // [B*C][K_PER] f32         128,000
#define OFF_WSIDX   1963008     // [B*C][K_PER] i32         128,000

typedef unsigned long long u64;
typedef unsigned int u32;

// LDS bank swizzle for u64 key array: bank16 rotates per 16-element group.
__device__ __forceinline__ int swz(int i) { return i + (i >> 4); }

// ---- monotone float <-> ordered-uint mapping (total order, bit-exact) ----
__device__ __forceinline__ u32 ford(float f) {
    u32 u = __float_as_uint(f);
    return (u & 0x80000000u) ? ~u : (u | 0x80000000u);
}
__device__ __forceinline__ float funord(u32 o) {
    u32 u = (o & 0x80000000u) ? (o ^ 0x80000000u) : ~o;
    return __uint_as_float(u);
}

// IoU>0.5 test, bit-identical to RN(inter/uni) > 0.5 but divide-free in the
// common case: ref kill <=> inter/uni > 0.5 + 2^-25 <=> 2*inter - uni >
// uni*2^-24. Near the boundary (2*inter in [uni/2, 2*uni]) the subtraction is
// Sterbenz-exact, so deciding by diff with a 2.4e-7 guard band is exact; only
// the ambiguous band 0 < diff <= uni*2.4e-7 falls back to the IEEE divide.
__device__ __forceinline__ bool iou_gt_fast(float4 a, float aa, float4 b, float ab) {
#pragma clang fp contract(off)
    float ih = fminf(a.z, b.z) - fmaxf(a.x, b.x); ih = fmaxf(ih, 0.0f);
    float iw = fminf(a.w, b.w) - fmaxf(a.y, b.y); iw = fmaxf(iw, 0.0f);
    float inter = ih * iw;
    float uni = fmaxf(aa + ab - inter, 1e-12f);
    float diff = 2.0f * inter - uni;
    bool kill = diff > uni * 2.4e-7f;
    if (__builtin_expect(!kill && diff > 0.0f, 0))
        kill = (inter / uni) > 0.5f;
    return kill;
}

// ---------------------------------------------------------------------------
// Single fused kernel (r19): one block per (image, class), 256 thr, 4 waves.
//  - r18-proven: LDS canon boxes, strided score load, bitonic sort, staged
//    double-buffered windows, parallel kill-mask prep, 1-wave accept loop.
//  - r19a: accept loop slimmed to pure bit ops (accept-mask + one batched
//    popcount-ranked commit per window; no per-iteration branches/LDS writes)
//  - r19b: divide-free exact IoU (see iou_gt_fast)
//  - r19c: final top-300 FUSED: last-finishing block per image (device-scope
//    atomic election + threadfence release/acquire) runs the proven radix
//    top-k inline, reusing the LDS arena. final_topk kernel deleted.
// ---------------------------------------------------------------------------
__global__ __launch_bounds__(256, 2) void nms_classes(
        const float* __restrict__ scores,   // [B, N, C]
        const float* __restrict__ boxes,    // [B, N, 1, 4]
        float* __restrict__ ws_score,       // [B*C*K_PER]
        int*   __restrict__ ws_idx,         // [B*C*K_PER]
        float* __restrict__ out,
        int*   __restrict__ done_cnt)       // [B_IMG], zeroed per launch
{
    // ---- LDS arena: nms phase (34304 B) and topk phase (40192 B) overlap ----
    __shared__ __align__(16) char smraw[40192];
    u64*    key  = (u64*)(smraw);                  // [KPAD]        8704
    float4* bx   = (float4*)(smraw + 8704);        // [N_BOX]      16384
    float*  ar   = (float*)(smraw + 25088);        // [N_BOX]       4096
    float4* wbuf = (float4*)(smraw + 29184);       // [2][64]       2048
    float*  wab  = (float*)(smraw + 31232);        // [2][64]        512
    float4* kb   = (float4*)(smraw + 31744);       // [128]         2048
    float*  ka   = (float*)(smraw + 33792);        // [128]          512

    __shared__ int    kept_t[K_PER];
    __shared__ u32    colk16[4][64];        // per-grp 16-bit kill rows
    __shared__ u64    sup64[4];             // per-wave suppressed ballots
    __shared__ int    sh_nvalid, sh_kept, sh_rank;
    __shared__ int    sh_sel, sh_cnt, sh_valid;
    __shared__ u32    sh_need;

    const int tid  = threadIdx.x;
    const int lane = tid & 63;
    const int b  = blockIdx.x / C_CLS;
    const int c  = blockIdx.x % C_CLS;

    if (tid == 0) { sh_nvalid = 0; sh_kept = 0; }

    // ---- canonical boxes + areas into LDS ----
    for (int n = tid; n < N_BOX; n += 256) {
        float4 v = ((const float4*)boxes)[b * N_BOX + n];
        {
#pragma clang fp contract(off)
            float y1 = fminf(v.x, v.z), y2 = fmaxf(v.x, v.z);
            float x1 = fminf(v.y, v.w), x2 = fmaxf(v.y, v.w);
            bx[n] = make_float4(y1, x1, y2, x2);
            ar[n] = (y2 - y1) * (x2 - x1);
        }
    }
    __syncthreads();

    // ---- load scores: strided scalar reads (L2/L3-resident) ----
    u64 r[4];
    {
        const float* sc = scores + (size_t)(b * N_BOX) * C_CLS + c;
        int lv = 0;
        #pragma unroll
        for (int q = 0; q < 4; ++q) {
            int v = tid * 4 + q;
            float s0 = sc[(size_t)v * C_CLS];
            bool valid = s0 > 0.001f;                  // SCORE_THR
            float s = valid ? s0 : NEGF;
            r[q] = ((u64)ford(s) << 32) | (u32)(N_BOX - 1 - v);  // stable ties
            lv += valid ? 1 : 0;
        }
        if (lv) atomicAdd(&sh_nvalid, lv);
    }

    // ---- register/shuffle bitonic sort, descending (proven network) ----
    #define CE(a, b, d) { u64 _mx = (a) > (b) ? (a) : (b); \
                          u64 _mn = (a) > (b) ? (b) : (a); \
                          (a) = (d) ? _mx : _mn; (b) = (d) ? _mn : _mx; }
    CE(r[0], r[1], true); CE(r[2], r[3], false);

    for (int k = 4; k <= N_BOX; k <<= 1) {
        const bool d = ((tid & (k >> 2)) == 0);
        for (int j = k >> 1; j > 0; j >>= 1) {
            if (j >= 256) {                          // cross-wave: LDS stage
                __syncthreads();
                #pragma unroll
                for (int q = 0; q < 4; ++q) key[swz(tid * 4 + q)] = r[q];
                __syncthreads();
                const bool upper = ((tid * 4) & j) != 0;
                #pragma unroll
                for (int q = 0; q < 4; ++q) {
                    u64 pv = key[swz((tid * 4 + q) ^ j)];
                    u64 mx = r[q] > pv ? r[q] : pv;
                    u64 mn = r[q] > pv ? pv : r[q];
                    r[q] = (d != upper) ? mx : mn;
                }
            } else if (j >= 4) {                     // intra-wave: shuffle
                const int dl = j >> 2;
                const bool upper = (lane & dl) != 0;
                #pragma unroll
                for (int q = 0; q < 4; ++q) {
                    u64 pv = __shfl_xor(r[q], dl);
                    u64 mx = r[q] > pv ? r[q] : pv;
                    u64 mn = r[q] > pv ? pv : r[q];
                    r[q] = (d != upper) ? mx : mn;
                }
            } else if (j == 2) {
                CE(r[0], r[2], d); CE(r[1], r[3], d);
            } else {
                CE(r[0], r[1], d); CE(r[2], r[3], d);
            }
        }
    }
    #undef CE

    __syncthreads();
    #pragma unroll
    for (int q = 0; q < 4; ++q) key[swz(tid * 4 + q)] = r[q];
    __syncthreads();

    // ---- prologue: stage window 0's boxes (wave 0) ----
    if (tid < 64) {
        u64 kv = key[swz(tid)];
        int idx = (N_BOX - 1) - (int)(u32)(kv & 0xFFFFFFFFu);
        wbuf[tid] = bx[idx];
        wab[tid]  = ar[idx];
    }

    const int nvalid = sh_nvalid;
    const int nwin = (nvalid + 63) >> 6;
    const int me  = tid & 63;               // candidate slot in window
    const int grp = tid >> 6;               // wave id 0..3

    for (int w = 0; w < nwin; ++w) {
        const int cur = w & 1;
        __syncthreads();                    // (A) staged boxes + kept stable
        if (sh_kept >= K_PER) break;        // wave-uniform
        const int kept0 = sh_kept;
        const int bt = w * 64;

        // stage NEXT window (wave 1) — chain hides under IoU VALU
        if (grp == 1 && (w + 1) < nwin) {
            u64 kv = key[swz((bt + 64 + me) & (N_BOX - 1))];
            int idx = (N_BOX - 1) - (int)(u32)(kv & 0xFFFFFFFFu);
            wbuf[(cur ^ 1) * 64 + me] = bx[idx];
            wab[(cur ^ 1) * 64 + me]  = ar[idx];
        }

        // my candidate
        const float4 qm = wbuf[cur * 64 + me];
        const float  am = wab[cur * 64 + me];

        // intra-window kill rows grp*16..+15: batch-load then compute
        {
            float4 wrow[16]; float warow[16];
            #pragma unroll
            for (int rq = 0; rq < 16; ++rq) {
                wrow[rq]  = wbuf[cur * 64 + grp * 16 + rq];
                warow[rq] = wab[cur * 64 + grp * 16 + rq];
            }
            u32 bits = 0;
            #pragma unroll
            for (int rq = 0; rq < 16; ++rq) {
                int rr = grp * 16 + rq;
                bool kill = (rr != me) && iou_gt_fast(wrow[rq], warow[rq], qm, am);
                bits |= ((u32)kill) << rq;
            }
            colk16[grp][me] = bits;                   // unique writer
        }

        // cross-window vs kept list: strided over waves, batch-8 loads
        {
            bool supme = false;
            for (int t0 = 0; grp + 4 * t0 < kept0; t0 += 8) {
                float4 kbl[8]; float kal[8];
                #pragma unroll
                for (int i = 0; i < 8; ++i) {
                    int k = grp + 4 * (t0 + i);       // <= 127, padded
                    kbl[i] = kb[k]; kal[i] = ka[k];
                }
                #pragma unroll
                for (int i = 0; i < 8; ++i) {
                    int k = grp + 4 * (t0 + i);
                    if (k < kept0 && iou_gt_fast(kbl[i], kal[i], qm, am)) supme = true;
                }
            }
            u64 bal = __ballot(supme);
            if (lane == 0) sup64[grp] = bal;
        }
        __syncthreads();                    // (C) masks ready

        // greedy accept loop: wave 0 only, slim bit-ops body (r19a)
        if (grp == 0) {
            u32 c0 = colk16[0][lane], c1 = colk16[1][lane];
            u32 c2 = colk16[2][lane], c3 = colk16[3][lane];
            u64 colkill = (u64)c0 | ((u64)c1 << 16)
                        | ((u64)c2 << 32) | ((u64)c3 << 48);
            u64 supp = sup64[0] | sup64[1] | sup64[2] | sup64[3];
            bool in = ((bt + lane) < nvalid) && !((supp >> lane) & 1ull);
            u64 pending = __ballot(in);
            int kept = kept0;
            u64 acc = 0;
            while (pending && kept < K_PER) {
                int t0 = __ffsll((long long)pending) - 1;   // wave-uniform
                acc |= 1ull << t0;
                kept++;
                bool kill = (colkill >> t0) & 1ull;
                pending &= ~(1ull << t0);
                pending &= ~__ballot(kill);
            }
            // batched commit: ffs order == ascending lane, so popcount ranks
            if ((acc >> lane) & 1ull) {
                int pos = kept0 + (int)__popcll(acc & ((1ull << lane) - 1ull));
                kept_t[pos] = bt + lane;
                kb[pos] = qm; ka[pos] = am;
            }
            if (lane == 0) sh_kept = kept;
        }
    }
    __syncthreads();

    const int kept = sh_kept;
    if (tid < K_PER) {
        int ob = (b * C_CLS + c) * K_PER + tid;
        if (tid < kept) {
            u64 k = key[swz(kept_t[tid])];
            ws_score[ob] = funord((u32)(k >> 32));
            ws_idx[ob]   = (N_BOX - 1) - (int)(u32)(k & 0xFFFFFFFFu);
        } else {
            ws_score[ob] = NEGF;
            ws_idx[ob]   = 0;
        }
    }

    // ================= fused final top-300 (winner block only) =============
    __syncthreads();                        // ws stores drained (vmcnt in barrier)
    if (tid == 0) {
        __threadfence();                    // release: publish ws to device
        sh_rank = atomicAdd(&done_cnt[b], 1);
    }
    __syncthreads();
    if (sh_rank != C_CLS - 1) return;       // block-uniform
    __threadfence();                        // acquire: see all classes' ws

    u32* skey  = (u32*)(smraw);             // [NCAND]  32000
    u32* hist4 = (u32*)(smraw + 32000);     // [1024]    4096
    u64* list  = (u64*)(smraw + 36096);     // [512]     4096

    const int base2 = b * NCAND;
    if (tid == 0) { sh_cnt = 0; sh_valid = 0; }
    for (int i = tid; i < NCAND; i += 256)
        skey[i] = ford(ws_score[base2 + i]);
    for (int i = tid; i < 512; i += 256) list[i] = 0;
    for (int i = tid; i < 1024; i += 256) hist4[i] = 0;
    __syncthreads();

    u64 prefix = 0;
    u32 need = K_TOT;
    const int rounds[6] = {7, 6, 5, 4, 1, 0};
    const int slot = tid & 3;

    for (int rd = 0; rd < 6; ++rd) {
        const int d = rounds[rd];
        for (int i = tid; i < NCAND; i += 256) {
            u64 k = ((u64)skey[i] << 32) | (u32)(M_SEL - 1 - i);
            // d==7 guard: shift by 64 is UB
            bool match = (d == 7) || (((k ^ prefix) >> (8 * (d + 1))) == 0);
            if (match)
                atomicAdd(&hist4[(((u32)(k >> (8 * d)) & 0xFFu) << 2) | slot], 1u);
        }
        __syncthreads();
        if (tid < 64) {
            const int l = tid;
            u32 h[4];
            #pragma unroll
            for (int q = 0; q < 4; ++q) {
                int bin = 4 * l + q;
                h[q] = hist4[bin * 4 + 0] + hist4[bin * 4 + 1]
                     + hist4[bin * 4 + 2] + hist4[bin * 4 + 3];
                hist4[bin * 4 + 0] = 0; hist4[bin * 4 + 1] = 0;
                hist4[bin * 4 + 2] = 0; hist4[bin * 4 + 3] = 0;
            }
            u32 s3 = h[3], s2 = h[2] + s3, s1 = h[1] + s2, s0 = h[0] + s1;
            u32 tot = s0, S = tot;
            #pragma unroll
            for (int off = 1; off < 64; off <<= 1) {
                u32 t = __shfl(S, (l + off) & 63);
                if (l + off < 64) S += t;
            }
            u32 T = S - tot;
            u32 sv0 = s0 + T, sv1 = s1 + T, sv2 = s2 + T, sv3 = s3 + T;
            if (sv0 >= need && sv1 < need) { sh_sel = 4*l;     sh_need = need - sv1; }
            if (sv1 >= need && sv2 < need) { sh_sel = 4*l + 1; sh_need = need - sv2; }
            if (sv2 >= need && sv3 < need) { sh_sel = 4*l + 2; sh_need = need - sv3; }
            if (sv3 >= need && T   < need) { sh_sel = 4*l + 3; sh_need = need - T;   }
        }
        __syncthreads();
        prefix |= ((u64)(u32)sh_sel) << (8 * d);
        need = sh_need;
        __syncthreads();
    }

    for (int i = tid; i < NCAND; i += 256) {
        u64 k = ((u64)skey[i] << 32) | (u32)(M_SEL - 1 - i);
        if (k >= prefix) {
            int p = atomicAdd(&sh_cnt, 1);
            if (p < 512) list[p] = k;
        }
    }
    __syncthreads();

    // one-wave register bitonic sort of list[512], descending (pads 0 last)
    if (tid < 64) {
        const int l = tid;
        u64 e[8];
        #pragma unroll
        for (int q = 0; q < 8; ++q) e[q] = list[l * 8 + q];
        #define CE2(a, b, dd) { u64 _mx = (a) > (b) ? (a) : (b); \
                                u64 _mn = (a) > (b) ? (b) : (a); \
                                (a) = (dd) ? _mx : _mn; (b) = (dd) ? _mn : _mx; }
        CE2(e[0], e[1], true);  CE2(e[2], e[3], false);
        CE2(e[4], e[5], true);  CE2(e[6], e[7], false);
        CE2(e[0], e[2], true);  CE2(e[1], e[3], true);
        CE2(e[4], e[6], false); CE2(e[5], e[7], false);
        CE2(e[0], e[1], true);  CE2(e[2], e[3], true);
        CE2(e[4], e[5], false); CE2(e[6], e[7], false);
        for (int k = 8; k <= 512; k <<= 1) {
            const bool d = ((l & (k >> 3)) == 0);
            for (int j = k >> 1; j >= 8; j >>= 1) {
                const int dl = j >> 3;
                const bool upper = (l & dl) != 0;
                #pragma unroll
                for (int q = 0; q < 8; ++q) {
                    u64 pv = __shfl_xor(e[q], dl);
                    u64 mx = e[q] > pv ? e[q] : pv;
                    u64 mn = e[q] > pv ? pv : e[q];
                    e[q] = (d != upper) ? mx : mn;
                }
            }
            CE2(e[0], e[4], d); CE2(e[1], e[5], d);
            CE2(e[2], e[6], d); CE2(e[3], e[7], d);
            CE2(e[0], e[2], d); CE2(e[1], e[3], d);
            CE2(e[4], e[6], d); CE2(e[5], e[7], d);
            CE2(e[0], e[1], d); CE2(e[2], e[3], d);
            CE2(e[4], e[5], d); CE2(e[6], e[7], d);
        }
        #undef CE2
        #pragma unroll
        for (int q = 0; q < 8; ++q) list[l * 8 + q] = e[q];
    }
    __syncthreads();

    float* out_s = out;                         // [B,300]
    float* out_b = out + B_IMG * K_TOT;         // [B,300,4]
    float* out_c = out + B_IMG * K_TOT * 5;     // [B,300]
    float* out_n = out + B_IMG * K_TOT * 6;     // [B]

    for (int i = tid; i < K_TOT; i += 256) {
        u64 k = list[i];
        float s = funord((u32)(k >> 32));
        int flat = (M_SEL - 1) - (int)(u32)(k & 0xFFFFFFFFu);
        bool valid = s > (-5e29f);              // top_s > NEG/2
        float os = 0.0f, oc = 0.0f;
        float4 obv = make_float4(0.0f, 0.0f, 0.0f, 0.0f);
        if (valid && flat < NCAND) {
            int cc = flat / K_PER;
            int n  = ws_idx[base2 + flat];
            float4 bb = ((const float4*)boxes)[b * N_BOX + n];
            os = s;
            oc = (float)cc;
            obv.x = fminf(fmaxf(bb.x, 0.0f), 1.0f);
            obv.y = fminf(fmaxf(bb.y, 0.0f), 1.0f);
            obv.z = fminf(fmaxf(bb.z, 0.0f), 1.0f);
            obv.w = fminf(fmaxf(bb.w, 0.0f), 1.0f);
            atomicAdd(&sh_valid, 1);
        }
        out_s[b * K_TOT + i] = os;
        ((float4*)out_b)[b * K_TOT + i] = obv;
        out_c[b * K_TOT + i] = oc;
    }
    __syncthreads();
    if (tid == 0) out_n[b] = (float)sh_valid;
}

extern "C" void kernel_launch(void* const* d_in, const int* in_sizes, int n_in,
                              void* d_out, int out_size, void* d_ws, size_t ws_size,
                              hipStream_t stream) {
    const float* scores = (const float*)d_in[0];   // [4,1024,80]
    const float* boxes  = (const float*)d_in[1];   // [4,1024,1,4]

    char* ws = (char*)d_ws;                        // footprint unchanged
    int*   done_cnt = (int*)(ws + OFF_DONE);
    float* ws_score = (float*)(ws + OFF_WSCORE);
    int*   ws_idx   = (int*)  (ws + OFF_WSIDX);

    hipMemsetAsync(done_cnt, 0, B_IMG * sizeof(int), stream);
    nms_classes<<<dim3(B_IMG * C_CLS), dim3(256), 0, stream>>>(
        scores, boxes, ws_score, ws_idx, (float*)d_out, done_cnt);
}

// Round 6
// 122.871 us; speedup vs baseline: 1.0359x; 1.0359x over previous
//
#include <hip/hip_runtime.h>
#include <stdint.h>

#define N_BOX 1024
#define C_CLS 80
#define B_IMG 4
#define K_PER 100
#define K_TOT 300
#define NEGF  (-1e30f)
#define NCAND (C_CLS * K_PER)    // 8000 candidates per image
#define M_SEL 8192               // flat-index packing base for final top-k
#define KPAD  1088               // 1024 + 64 swizzle pad

// workspace layout (bytes) — proven offsets; done_cnt claims bytes [0,16)
#define OFF_DONE    0            // int[4] per-image completion counters
#define OFF_WSCORE  1835008     // [B*C][K_PER] f32         128,000
#define OFF_WSIDX   1963008     // [B*C][K_PER] i32         128,000

typedef unsigned long long u64;
typedef unsigned int u32;

// LDS bank swizzle for u64 key array: bank16 rotates per 16-element group.
__device__ __forceinline__ int swz(int i) { return i + (i >> 4); }

// ---- monotone float <-> ordered-uint mapping (total order, bit-exact) ----
__device__ __forceinline__ u32 ford(float f) {
    u32 u = __float_as_uint(f);
    return (u & 0x80000000u) ? ~u : (u | 0x80000000u);
}
__device__ __forceinline__ float funord(u32 o) {
    u32 u = (o & 0x80000000u) ? (o ^ 0x80000000u) : ~o;
    return __uint_as_float(u);
}

// IoU>0.5 test, bit-identical to RN(inter/uni) > 0.5 but divide-free in the
// common case (Sterbenz-exact diff + guard band; divide only in the ambiguous
// band). Proven bit-exact in r19 (absmax 0).
__device__ __forceinline__ bool iou_gt_fast(float4 a, float aa, float4 b, float ab) {
#pragma clang fp contract(off)
    float ih = fminf(a.z, b.z) - fmaxf(a.x, b.x); ih = fmaxf(ih, 0.0f);
    float iw = fminf(a.w, b.w) - fmaxf(a.y, b.y); iw = fmaxf(iw, 0.0f);
    float inter = ih * iw;
    float uni = fmaxf(aa + ab - inter, 1e-12f);
    float diff = 2.0f * inter - uni;
    bool kill = diff > uni * 2.4e-7f;
    if (__builtin_expect(!kill && diff > 0.0f, 0))
        kill = (inter / uni) > 0.5f;
    return kill;
}

// ---------------------------------------------------------------------------
// Single fused kernel (r20): one block per (image, class), 256 thr, 4 waves.
// r19 regression fixed:
//  - ALL LDS arrays named (no char-arena pointer aliasing) — nms phase and
//    topk phase coexist at 75.9 KB (still 2 blocks/CU).
//  - winner-block top-k tail de-latencied: float4 skey staging + 4-deep
//    batched loads in every radix scan / collect pass (the r15 fix applied
//    to the tail's dependent load->atomic chains).
// Everything else verbatim from r19 (passed bit-exact).
// ---------------------------------------------------------------------------
__global__ __launch_bounds__(256, 2) void nms_classes(
        const float* __restrict__ scores,   // [B, N, C]
        const float* __restrict__ boxes,    // [B, N, 1, 4]
        float* __restrict__ ws_score,       // [B*C*K_PER]
        int*   __restrict__ ws_idx,         // [B*C*K_PER]
        float* __restrict__ out,
        int*   __restrict__ done_cnt)       // [B_IMG], zeroed per launch
{
    // nms phase
    __shared__ u64    key[KPAD];            // 8704 B (swizzled)
    __shared__ float4 bx[N_BOX];            // 16384
    __shared__ float  ar[N_BOX];            // 4096
    __shared__ float4 wbuf[2][64];          // 2048
    __shared__ float  wab[2][64];           // 512
    __shared__ float4 kb[128];              // 2048 (padded for batch-8)
    __shared__ float  ka[128];              // 512
    __shared__ int    kept_t[K_PER];
    __shared__ u32    colk16[4][64];        // per-grp 16-bit kill rows
    __shared__ u64    sup64[4];             // per-wave suppressed ballots
    __shared__ int    sh_nvalid, sh_kept, sh_rank;
    // topk phase (separate named arrays — alias-clean)
    __shared__ u32    skey[NCAND];          // 32000
    __shared__ u32    hist4[1024];          // 4096
    __shared__ u64    list[512];            // 4096
    __shared__ int    sh_sel, sh_cnt, sh_valid;
    __shared__ u32    sh_need;

    const int tid  = threadIdx.x;
    const int lane = tid & 63;
    const int b  = blockIdx.x / C_CLS;
    const int c  = blockIdx.x % C_CLS;

    if (tid == 0) { sh_nvalid = 0; sh_kept = 0; }

    // ---- canonical boxes + areas into LDS ----
    for (int n = tid; n < N_BOX; n += 256) {
        float4 v = ((const float4*)boxes)[b * N_BOX + n];
        {
#pragma clang fp contract(off)
            float y1 = fminf(v.x, v.z), y2 = fmaxf(v.x, v.z);
            float x1 = fminf(v.y, v.w), x2 = fmaxf(v.y, v.w);
            bx[n] = make_float4(y1, x1, y2, x2);
            ar[n] = (y2 - y1) * (x2 - x1);
        }
    }
    __syncthreads();

    // ---- load scores: strided scalar reads (L2/L3-resident) ----
    u64 r[4];
    {
        const float* sc = scores + (size_t)(b * N_BOX) * C_CLS + c;
        int lv = 0;
        #pragma unroll
        for (int q = 0; q < 4; ++q) {
            int v = tid * 4 + q;
            float s0 = sc[(size_t)v * C_CLS];
            bool valid = s0 > 0.001f;                  // SCORE_THR
            float s = valid ? s0 : NEGF;
            r[q] = ((u64)ford(s) << 32) | (u32)(N_BOX - 1 - v);  // stable ties
            lv += valid ? 1 : 0;
        }
        if (lv) atomicAdd(&sh_nvalid, lv);
    }

    // ---- register/shuffle bitonic sort, descending (proven network) ----
    #define CE(a, b, d) { u64 _mx = (a) > (b) ? (a) : (b); \
                          u64 _mn = (a) > (b) ? (b) : (a); \
                          (a) = (d) ? _mx : _mn; (b) = (d) ? _mn : _mx; }
    CE(r[0], r[1], true); CE(r[2], r[3], false);

    for (int k = 4; k <= N_BOX; k <<= 1) {
        const bool d = ((tid & (k >> 2)) == 0);
        for (int j = k >> 1; j > 0; j >>= 1) {
            if (j >= 256) {                          // cross-wave: LDS stage
                __syncthreads();
                #pragma unroll
                for (int q = 0; q < 4; ++q) key[swz(tid * 4 + q)] = r[q];
                __syncthreads();
                const bool upper = ((tid * 4) & j) != 0;
                #pragma unroll
                for (int q = 0; q < 4; ++q) {
                    u64 pv = key[swz((tid * 4 + q) ^ j)];
                    u64 mx = r[q] > pv ? r[q] : pv;
                    u64 mn = r[q] > pv ? pv : r[q];
                    r[q] = (d != upper) ? mx : mn;
                }
            } else if (j >= 4) {                     // intra-wave: shuffle
                const int dl = j >> 2;
                const bool upper = (lane & dl) != 0;
                #pragma unroll
                for (int q = 0; q < 4; ++q) {
                    u64 pv = __shfl_xor(r[q], dl);
                    u64 mx = r[q] > pv ? r[q] : pv;
                    u64 mn = r[q] > pv ? pv : r[q];
                    r[q] = (d != upper) ? mx : mn;
                }
            } else if (j == 2) {
                CE(r[0], r[2], d); CE(r[1], r[3], d);
            } else {
                CE(r[0], r[1], d); CE(r[2], r[3], d);
            }
        }
    }
    #undef CE

    __syncthreads();
    #pragma unroll
    for (int q = 0; q < 4; ++q) key[swz(tid * 4 + q)] = r[q];
    __syncthreads();

    // ---- prologue: stage window 0's boxes (wave 0) ----
    if (tid < 64) {
        u64 kv = key[swz(tid)];
        int idx = (N_BOX - 1) - (int)(u32)(kv & 0xFFFFFFFFu);
        wbuf[0][tid] = bx[idx];
        wab[0][tid]  = ar[idx];
    }

    const int nvalid = sh_nvalid;
    const int nwin = (nvalid + 63) >> 6;
    const int me  = tid & 63;               // candidate slot in window
    const int grp = tid >> 6;               // wave id 0..3

    for (int w = 0; w < nwin; ++w) {
        const int cur = w & 1;
        __syncthreads();                    // (A) staged boxes + kept stable
        if (sh_kept >= K_PER) break;        // wave-uniform
        const int kept0 = sh_kept;
        const int bt = w * 64;

        // stage NEXT window (wave 1) — chain hides under IoU VALU
        if (grp == 1 && (w + 1) < nwin) {
            u64 kv = key[swz((bt + 64 + me) & (N_BOX - 1))];
            int idx = (N_BOX - 1) - (int)(u32)(kv & 0xFFFFFFFFu);
            wbuf[cur ^ 1][me] = bx[idx];
            wab[cur ^ 1][me]  = ar[idx];
        }

        // my candidate
        const float4 qm = wbuf[cur][me];
        const float  am = wab[cur][me];

        // intra-window kill rows grp*16..+15: batch-load then compute
        {
            float4 wrow[16]; float warow[16];
            #pragma unroll
            for (int rq = 0; rq < 16; ++rq) {
                wrow[rq]  = wbuf[cur][grp * 16 + rq];
                warow[rq] = wab[cur][grp * 16 + rq];
            }
            u32 bits = 0;
            #pragma unroll
            for (int rq = 0; rq < 16; ++rq) {
                int rr = grp * 16 + rq;
                bool kill = (rr != me) && iou_gt_fast(wrow[rq], warow[rq], qm, am);
                bits |= ((u32)kill) << rq;
            }
            colk16[grp][me] = bits;                   // unique writer
        }

        // cross-window vs kept list: strided over waves, batch-8 loads
        {
            bool supme = false;
            for (int t0 = 0; grp + 4 * t0 < kept0; t0 += 8) {
                float4 kbl[8]; float kal[8];
                #pragma unroll
                for (int i = 0; i < 8; ++i) {
                    int k = grp + 4 * (t0 + i);       // <= 127, padded
                    kbl[i] = kb[k]; kal[i] = ka[k];
                }
                #pragma unroll
                for (int i = 0; i < 8; ++i) {
                    int k = grp + 4 * (t0 + i);
                    if (k < kept0 && iou_gt_fast(kbl[i], kal[i], qm, am)) supme = true;
                }
            }
            u64 bal = __ballot(supme);
            if (lane == 0) sup64[grp] = bal;
        }
        __syncthreads();                    // (C) masks ready

        // greedy accept loop: wave 0 only, slim bit-ops body
        if (grp == 0) {
            u32 c0 = colk16[0][lane], c1 = colk16[1][lane];
            u32 c2 = colk16[2][lane], c3 = colk16[3][lane];
            u64 colkill = (u64)c0 | ((u64)c1 << 16)
                        | ((u64)c2 << 32) | ((u64)c3 << 48);
            u64 supp = sup64[0] | sup64[1] | sup64[2] | sup64[3];
            bool in = ((bt + lane) < nvalid) && !((supp >> lane) & 1ull);
            u64 pending = __ballot(in);
            int kept = kept0;
            u64 acc = 0;
            while (pending && kept < K_PER) {
                int t0 = __ffsll((long long)pending) - 1;   // wave-uniform
                acc |= 1ull << t0;
                kept++;
                bool kill = (colkill >> t0) & 1ull;
                pending &= ~(1ull << t0);
                pending &= ~__ballot(kill);
            }
            // batched commit: ffs order == ascending lane, so popcount ranks
            if ((acc >> lane) & 1ull) {
                int pos = kept0 + (int)__popcll(acc & ((1ull << lane) - 1ull));
                kept_t[pos] = bt + lane;
                kb[pos] = qm; ka[pos] = am;
            }
            if (lane == 0) sh_kept = kept;
        }
    }
    __syncthreads();

    const int kept = sh_kept;
    if (tid < K_PER) {
        int ob = (b * C_CLS + c) * K_PER + tid;
        if (tid < kept) {
            u64 k = key[swz(kept_t[tid])];
            ws_score[ob] = funord((u32)(k >> 32));
            ws_idx[ob]   = (N_BOX - 1) - (int)(u32)(k & 0xFFFFFFFFu);
        } else {
            ws_score[ob] = NEGF;
            ws_idx[ob]   = 0;
        }
    }

    // ================= fused final top-300 (winner block only) =============
    __syncthreads();                        // ws stores drained
    if (tid == 0) {
        __threadfence();                    // release: publish ws to device
        sh_rank = atomicAdd(&done_cnt[b], 1);
    }
    __syncthreads();
    if (sh_rank != C_CLS - 1) return;       // block-uniform
    __threadfence();                        // acquire: see all classes' ws

    const int base2 = b * NCAND;
    if (tid == 0) { sh_cnt = 0; sh_valid = 0; }
    // float4 skey staging (2000 vector loads)
    for (int i = tid; i < NCAND / 4; i += 256) {
        float4 s4 = ((const float4*)(ws_score + base2))[i];
        skey[4 * i + 0] = ford(s4.x);
        skey[4 * i + 1] = ford(s4.y);
        skey[4 * i + 2] = ford(s4.z);
        skey[4 * i + 3] = ford(s4.w);
    }
    for (int i = tid; i < 512; i += 256) list[i] = 0;
    for (int i = tid; i < 1024; i += 256) hist4[i] = 0;
    __syncthreads();

    u64 prefix = 0;
    u32 need = K_TOT;
    const int rounds[6] = {7, 6, 5, 4, 1, 0};
    const int slot = tid & 3;

    for (int rd = 0; rd < 6; ++rd) {
        const int d = rounds[rd];
        // 4-deep batched scan: 4 independent LDS loads per waitcnt
        for (int i0 = 0; i0 < NCAND; i0 += 1024) {
            u32 kv[4];
            #pragma unroll
            for (int q = 0; q < 4; ++q) {
                int i = i0 + tid + q * 256;
                kv[q] = (i < NCAND) ? skey[i] : 0u;
            }
            #pragma unroll
            for (int q = 0; q < 4; ++q) {
                int i = i0 + tid + q * 256;
                if (i < NCAND) {
                    u64 k = ((u64)kv[q] << 32) | (u32)(M_SEL - 1 - i);
                    // d==7 guard: shift by 64 is UB (short-circuit protects)
                    bool match = (d == 7) || (((k ^ prefix) >> (8 * (d + 1))) == 0);
                    if (match)
                        atomicAdd(&hist4[(((u32)(k >> (8 * d)) & 0xFFu) << 2) | slot], 1u);
                }
            }
        }
        __syncthreads();
        if (tid < 64) {
            const int l = tid;
            u32 h[4];
            #pragma unroll
            for (int q = 0; q < 4; ++q) {
                int bin = 4 * l + q;
                h[q] = hist4[bin * 4 + 0] + hist4[bin * 4 + 1]
                     + hist4[bin * 4 + 2] + hist4[bin * 4 + 3];
                hist4[bin * 4 + 0] = 0; hist4[bin * 4 + 1] = 0;
                hist4[bin * 4 + 2] = 0; hist4[bin * 4 + 3] = 0;
            }
            u32 s3 = h[3], s2 = h[2] + s3, s1 = h[1] + s2, s0 = h[0] + s1;
            u32 tot = s0, S = tot;
            #pragma unroll
            for (int off = 1; off < 64; off <<= 1) {
                u32 t = __shfl(S, (l + off) & 63);
                if (l + off < 64) S += t;
            }
            u32 T = S - tot;
            u32 sv0 = s0 + T, sv1 = s1 + T, sv2 = s2 + T, sv3 = s3 + T;
            if (sv0 >= need && sv1 < need) { sh_sel = 4*l;     sh_need = need - sv1; }
            if (sv1 >= need && sv2 < need) { sh_sel = 4*l + 1; sh_need = need - sv2; }
            if (sv2 >= need && sv3 < need) { sh_sel = 4*l + 2; sh_need = need - sv3; }
            if (sv3 >= need && T   < need) { sh_sel = 4*l + 3; sh_need = need - T;   }
        }
        __syncthreads();
        prefix |= ((u64)(u32)sh_sel) << (8 * d);
        need = sh_need;
        __syncthreads();
    }

    // collect pass, 4-deep batched
    for (int i0 = 0; i0 < NCAND; i0 += 1024) {
        u32 kv[4];
        #pragma unroll
        for (int q = 0; q < 4; ++q) {
            int i = i0 + tid + q * 256;
            kv[q] = (i < NCAND) ? skey[i] : 0u;
        }
        #pragma unroll
        for (int q = 0; q < 4; ++q) {
            int i = i0 + tid + q * 256;
            if (i < NCAND) {
                u64 k = ((u64)kv[q] << 32) | (u32)(M_SEL - 1 - i);
                if (k >= prefix) {
                    int p = atomicAdd(&sh_cnt, 1);
                    if (p < 512) list[p] = k;
                }
            }
        }
    }
    __syncthreads();

    // one-wave register bitonic sort of list[512], descending (pads 0 last)
    if (tid < 64) {
        const int l = tid;
        u64 e[8];
        #pragma unroll
        for (int q = 0; q < 8; ++q) e[q] = list[l * 8 + q];
        #define CE2(a, b, dd) { u64 _mx = (a) > (b) ? (a) : (b); \
                                u64 _mn = (a) > (b) ? (b) : (a); \
                                (a) = (dd) ? _mx : _mn; (b) = (dd) ? _mn : _mx; }
        CE2(e[0], e[1], true);  CE2(e[2], e[3], false);
        CE2(e[4], e[5], true);  CE2(e[6], e[7], false);
        CE2(e[0], e[2], true);  CE2(e[1], e[3], true);
        CE2(e[4], e[6], false); CE2(e[5], e[7], false);
        CE2(e[0], e[1], true);  CE2(e[2], e[3], true);
        CE2(e[4], e[5], false); CE2(e[6], e[7], false);
        for (int k = 8; k <= 512; k <<= 1) {
            const bool d = ((l & (k >> 3)) == 0);
            for (int j = k >> 1; j >= 8; j >>= 1) {
                const int dl = j >> 3;
                const bool upper = (l & dl) != 0;
                #pragma unroll
                for (int q = 0; q < 8; ++q) {
                    u64 pv = __shfl_xor(e[q], dl);
                    u64 mx = e[q] > pv ? e[q] : pv;
                    u64 mn = e[q] > pv ? pv : e[q];
                    e[q] = (d != upper) ? mx : mn;
                }
            }
            CE2(e[0], e[4], d); CE2(e[1], e[5], d);
            CE2(e[2], e[6], d); CE2(e[3], e[7], d);
            CE2(e[0], e[2], d); CE2(e[1], e[3], d);
            CE2(e[4], e[6], d); CE2(e[5], e[7], d);
            CE2(e[0], e[1], d); CE2(e[2], e[3], d);
            CE2(e[4], e[5], d); CE2(e[6], e[7], d);
        }
        #undef CE2
        #pragma unroll
        for (int q = 0; q < 8; ++q) list[l * 8 + q] = e[q];
    }
    __syncthreads();

    float* out_s = out;                         // [B,300]
    float* out_b = out + B_IMG * K_TOT;         // [B,300,4]
    float* out_c = out + B_IMG * K_TOT * 5;     // [B,300]
    float* out_n = out + B_IMG * K_TOT * 6;     // [B]

    for (int i = tid; i < K_TOT; i += 256) {
        u64 k = list[i];
        float s = funord((u32)(k >> 32));
        int flat = (M_SEL - 1) - (int)(u32)(k & 0xFFFFFFFFu);
        bool valid = s > (-5e29f);              // top_s > NEG/2
        float os = 0.0f, oc = 0.0f;
        float4 obv = make_float4(0.0f, 0.0f, 0.0f, 0.0f);
        if (valid && flat < NCAND) {
            int cc = flat / K_PER;
            int n  = ws_idx[base2 + flat];
            float4 bb = ((const float4*)boxes)[b * N_BOX + n];
            os = s;
            oc = (float)cc;
            obv.x = fminf(fmaxf(bb.x, 0.0f), 1.0f);
            obv.y = fminf(fmaxf(bb.y, 0.0f), 1.0f);
            obv.z = fminf(fmaxf(bb.z, 0.0f), 1.0f);
            obv.w = fminf(fmaxf(bb.w, 0.0f), 1.0f);
            atomicAdd(&sh_valid, 1);
        }
        out_s[b * K_TOT + i] = os;
        ((float4*)out_b)[b * K_TOT + i] = obv;
        out_c[b * K_TOT + i] = oc;
    }
    __syncthreads();
    if (tid == 0) out_n[b] = (float)sh_valid;
}

extern "C" void kernel_launch(void* const* d_in, const int* in_sizes, int n_in,
                              void* d_out, int out_size, void* d_ws, size_t ws_size,
                              hipStream_t stream) {
    const float* scores = (const float*)d_in[0];   // [4,1024,80]
    const float* boxes  = (const float*)d_in[1];   // [4,1024,1,4]

    char* ws = (char*)d_ws;                        // footprint unchanged
    int*   done_cnt = (int*)(ws + OFF_DONE);
    float* ws_score = (float*)(ws + OFF_WSCORE);
    int*   ws_idx   = (int*)  (ws + OFF_WSIDX);

    hipMemsetAsync(done_cnt, 0, B_IMG * sizeof(int), stream);
    nms_classes<<<dim3(B_IMG * C_CLS), dim3(256), 0, stream>>>(
        scores, boxes, ws_score, ws_idx, (float*)d_out, done_cnt);
}

// Round 7
// 120.096 us; speedup vs baseline: 1.0599x; 1.0231x over previous
//
#include <hip/hip_runtime.h>
#include <stdint.h>

#define N_BOX 1024
#define C_CLS 80
#define B_IMG 4
#define K_PER 100
#define K_TOT 300
#define NEGF  (-1e30f)
#define NCAND (C_CLS * K_PER)    // 8000 candidates per image
#define M_SEL 8192               // flat-index packing base for final top-k
#define KPAD  1088               // 1024 + 64 swizzle pad
#define EQCAP 768                // compacted equal-prefix16 candidate cap

// workspace layout (bytes) — proven offsets; done_cnt claims bytes [0,16)
#define OFF_DONE    0            // int[4] per-image completion counters
#define OFF_WSCORE  1835008     // [B*C][K_PER] f32         128,000
#define OFF_WSIDX   1963008     // [B*C][K_PER] i32         128,000

typedef unsigned long long u64;
typedef unsigned int u32;

// LDS bank swizzle for u64 key array: bank16 rotates per 16-element group.
__device__ __forceinline__ int swz(int i) { return i + (i >> 4); }

// ---- monotone float <-> ordered-uint mapping (total order, bit-exact) ----
__device__ __forceinline__ u32 ford(float f) {
    u32 u = __float_as_uint(f);
    return (u & 0x80000000u) ? ~u : (u | 0x80000000u);
}
__device__ __forceinline__ float funord(u32 o) {
    u32 u = (o & 0x80000000u) ? (o ^ 0x80000000u) : ~o;
    return __uint_as_float(u);
}

// IoU>0.5 test, bit-identical to RN(inter/uni) > 0.5 but divide-free in the
// common case (Sterbenz-exact diff + guard band; divide only in the ambiguous
// band). Proven bit-exact in r19/r20 (absmax 0).
__device__ __forceinline__ bool iou_gt_fast(float4 a, float aa, float4 b, float ab) {
#pragma clang fp contract(off)
    float ih = fminf(a.z, b.z) - fmaxf(a.x, b.x); ih = fmaxf(ih, 0.0f);
    float iw = fminf(a.w, b.w) - fmaxf(a.y, b.y); iw = fmaxf(iw, 0.0f);
    float inter = ih * iw;
    float uni = fmaxf(aa + ab - inter, 1e-12f);
    float diff = 2.0f * inter - uni;
    bool kill = diff > uni * 2.4e-7f;
    if (__builtin_expect(!kill && diff > 0.0f, 0))
        kill = (inter / uni) > 0.5f;
    return kill;
}

// ---------------------------------------------------------------------------
// Single fused kernel (r21): one block per (image, class), 256 thr, 4 waves.
// nms phase verbatim from r20 (proven). Winner-block top-300 tail compressed:
//   passes d=7,d=6 full (8000); then ONE compaction pass appends the <=299
//   strictly-above-prefix16 keys to `list` (guaranteed members, cnt=300-need)
//   and gathers equal-prefix16 candidate indices into eq[768]; rounds
//   {5,4,1,0} + collect then scan eq only (~25 entries typ). Overflow of eq
//   (tie-pathological) falls back to the original full-scan path. Bit-exact.
// ---------------------------------------------------------------------------
__global__ __launch_bounds__(256, 2) void nms_classes(
        const float* __restrict__ scores,   // [B, N, C]
        const float* __restrict__ boxes,    // [B, N, 1, 4]
        float* __restrict__ ws_score,       // [B*C*K_PER]
        int*   __restrict__ ws_idx,         // [B*C*K_PER]
        float* __restrict__ out,
        int*   __restrict__ done_cnt)       // [B_IMG], zeroed per launch
{
    // nms phase
    __shared__ u64    key[KPAD];            // 8704 B (swizzled)
    __shared__ float4 bx[N_BOX];            // 16384
    __shared__ float  ar[N_BOX];            // 4096
    __shared__ float4 wbuf[2][64];          // 2048
    __shared__ float  wab[2][64];           // 512
    __shared__ float4 kb[128];              // 2048 (padded for batch-8)
    __shared__ float  ka[128];              // 512
    __shared__ int    kept_t[K_PER];
    __shared__ u32    colk16[4][64];        // per-grp 16-bit kill rows
    __shared__ u64    sup64[4];             // per-wave suppressed ballots
    __shared__ int    sh_nvalid, sh_kept, sh_rank;
    // topk phase
    __shared__ u32    skey[NCAND];          // 32000
    __shared__ u32    hist4[1024];          // 4096
    __shared__ u64    list[512];            // 4096
    __shared__ u32    eq[EQCAP];            // 3072 — equal-prefix16 indices
    __shared__ int    sh_sel, sh_cnt, sh_valid, sh_eqcnt;
    __shared__ u32    sh_need;

    const int tid  = threadIdx.x;
    const int lane = tid & 63;
    const int b  = blockIdx.x / C_CLS;
    const int c  = blockIdx.x % C_CLS;

    if (tid == 0) { sh_nvalid = 0; sh_kept = 0; }

    // ---- canonical boxes + areas into LDS ----
    for (int n = tid; n < N_BOX; n += 256) {
        float4 v = ((const float4*)boxes)[b * N_BOX + n];
        {
#pragma clang fp contract(off)
            float y1 = fminf(v.x, v.z), y2 = fmaxf(v.x, v.z);
            float x1 = fminf(v.y, v.w), x2 = fmaxf(v.y, v.w);
            bx[n] = make_float4(y1, x1, y2, x2);
            ar[n] = (y2 - y1) * (x2 - x1);
        }
    }
    __syncthreads();

    // ---- load scores: strided scalar reads (L2/L3-resident) ----
    u64 r[4];
    {
        const float* sc = scores + (size_t)(b * N_BOX) * C_CLS + c;
        int lv = 0;
        #pragma unroll
        for (int q = 0; q < 4; ++q) {
            int v = tid * 4 + q;
            float s0 = sc[(size_t)v * C_CLS];
            bool valid = s0 > 0.001f;                  // SCORE_THR
            float s = valid ? s0 : NEGF;
            r[q] = ((u64)ford(s) << 32) | (u32)(N_BOX - 1 - v);  // stable ties
            lv += valid ? 1 : 0;
        }
        if (lv) atomicAdd(&sh_nvalid, lv);
    }

    // ---- register/shuffle bitonic sort, descending (proven network) ----
    #define CE(a, b, d) { u64 _mx = (a) > (b) ? (a) : (b); \
                          u64 _mn = (a) > (b) ? (b) : (a); \
                          (a) = (d) ? _mx : _mn; (b) = (d) ? _mn : _mx; }
    CE(r[0], r[1], true); CE(r[2], r[3], false);

    for (int k = 4; k <= N_BOX; k <<= 1) {
        const bool d = ((tid & (k >> 2)) == 0);
        for (int j = k >> 1; j > 0; j >>= 1) {
            if (j >= 256) {                          // cross-wave: LDS stage
                __syncthreads();
                #pragma unroll
                for (int q = 0; q < 4; ++q) key[swz(tid * 4 + q)] = r[q];
                __syncthreads();
                const bool upper = ((tid * 4) & j) != 0;
                #pragma unroll
                for (int q = 0; q < 4; ++q) {
                    u64 pv = key[swz((tid * 4 + q) ^ j)];
                    u64 mx = r[q] > pv ? r[q] : pv;
                    u64 mn = r[q] > pv ? pv : r[q];
                    r[q] = (d != upper) ? mx : mn;
                }
            } else if (j >= 4) {                     // intra-wave: shuffle
                const int dl = j >> 2;
                const bool upper = (lane & dl) != 0;
                #pragma unroll
                for (int q = 0; q < 4; ++q) {
                    u64 pv = __shfl_xor(r[q], dl);
                    u64 mx = r[q] > pv ? r[q] : pv;
                    u64 mn = r[q] > pv ? pv : r[q];
                    r[q] = (d != upper) ? mx : mn;
                }
            } else if (j == 2) {
                CE(r[0], r[2], d); CE(r[1], r[3], d);
            } else {
                CE(r[0], r[1], d); CE(r[2], r[3], d);
            }
        }
    }
    #undef CE

    __syncthreads();
    #pragma unroll
    for (int q = 0; q < 4; ++q) key[swz(tid * 4 + q)] = r[q];
    __syncthreads();

    // ---- prologue: stage window 0's boxes (wave 0) ----
    if (tid < 64) {
        u64 kv = key[swz(tid)];
        int idx = (N_BOX - 1) - (int)(u32)(kv & 0xFFFFFFFFu);
        wbuf[0][tid] = bx[idx];
        wab[0][tid]  = ar[idx];
    }

    const int nvalid = sh_nvalid;
    const int nwin = (nvalid + 63) >> 6;
    const int me  = tid & 63;               // candidate slot in window
    const int grp = tid >> 6;               // wave id 0..3

    for (int w = 0; w < nwin; ++w) {
        const int cur = w & 1;
        __syncthreads();                    // (A) staged boxes + kept stable
        if (sh_kept >= K_PER) break;        // wave-uniform
        const int kept0 = sh_kept;
        const int bt = w * 64;

        // stage NEXT window (wave 1) — chain hides under IoU VALU
        if (grp == 1 && (w + 1) < nwin) {
            u64 kv = key[swz((bt + 64 + me) & (N_BOX - 1))];
            int idx = (N_BOX - 1) - (int)(u32)(kv & 0xFFFFFFFFu);
            wbuf[cur ^ 1][me] = bx[idx];
            wab[cur ^ 1][me]  = ar[idx];
        }

        // my candidate
        const float4 qm = wbuf[cur][me];
        const float  am = wab[cur][me];

        // intra-window kill rows grp*16..+15: batch-load then compute
        {
            float4 wrow[16]; float warow[16];
            #pragma unroll
            for (int rq = 0; rq < 16; ++rq) {
                wrow[rq]  = wbuf[cur][grp * 16 + rq];
                warow[rq] = wab[cur][grp * 16 + rq];
            }
            u32 bits = 0;
            #pragma unroll
            for (int rq = 0; rq < 16; ++rq) {
                int rr = grp * 16 + rq;
                bool kill = (rr != me) && iou_gt_fast(wrow[rq], warow[rq], qm, am);
                bits |= ((u32)kill) << rq;
            }
            colk16[grp][me] = bits;                   // unique writer
        }

        // cross-window vs kept list: strided over waves, batch-8 loads
        {
            bool supme = false;
            for (int t0 = 0; grp + 4 * t0 < kept0; t0 += 8) {
                float4 kbl[8]; float kal[8];
                #pragma unroll
                for (int i = 0; i < 8; ++i) {
                    int k = grp + 4 * (t0 + i);       // <= 127, padded
                    kbl[i] = kb[k]; kal[i] = ka[k];
                }
                #pragma unroll
                for (int i = 0; i < 8; ++i) {
                    int k = grp + 4 * (t0 + i);
                    if (k < kept0 && iou_gt_fast(kbl[i], kal[i], qm, am)) supme = true;
                }
            }
            u64 bal = __ballot(supme);
            if (lane == 0) sup64[grp] = bal;
        }
        __syncthreads();                    // (C) masks ready

        // greedy accept loop: wave 0 only, slim bit-ops body
        if (grp == 0) {
            u32 c0 = colk16[0][lane], c1 = colk16[1][lane];
            u32 c2 = colk16[2][lane], c3 = colk16[3][lane];
            u64 colkill = (u64)c0 | ((u64)c1 << 16)
                        | ((u64)c2 << 32) | ((u64)c3 << 48);
            u64 supp = sup64[0] | sup64[1] | sup64[2] | sup64[3];
            bool in = ((bt + lane) < nvalid) && !((supp >> lane) & 1ull);
            u64 pending = __ballot(in);
            int kept = kept0;
            u64 acc = 0;
            while (pending && kept < K_PER) {
                int t0 = __ffsll((long long)pending) - 1;   // wave-uniform
                acc |= 1ull << t0;
                kept++;
                bool kill = (colkill >> t0) & 1ull;
                pending &= ~(1ull << t0);
                pending &= ~__ballot(kill);
            }
            // batched commit: ffs order == ascending lane, so popcount ranks
            if ((acc >> lane) & 1ull) {
                int pos = kept0 + (int)__popcll(acc & ((1ull << lane) - 1ull));
                kept_t[pos] = bt + lane;
                kb[pos] = qm; ka[pos] = am;
            }
            if (lane == 0) sh_kept = kept;
        }
    }
    __syncthreads();

    const int kept = sh_kept;
    if (tid < K_PER) {
        int ob = (b * C_CLS + c) * K_PER + tid;
        if (tid < kept) {
            u64 k = key[swz(kept_t[tid])];
            ws_score[ob] = funord((u32)(k >> 32));
            ws_idx[ob]   = (N_BOX - 1) - (int)(u32)(k & 0xFFFFFFFFu);
        } else {
            ws_score[ob] = NEGF;
            ws_idx[ob]   = 0;
        }
    }

    // ================= fused final top-300 (winner block only) =============
    __syncthreads();                        // ws stores drained
    if (tid == 0) {
        __threadfence();                    // release: publish ws to device
        sh_rank = atomicAdd(&done_cnt[b], 1);
    }
    __syncthreads();
    if (sh_rank != C_CLS - 1) return;       // block-uniform
    __threadfence();                        // acquire: see all classes' ws

    const int base2 = b * NCAND;
    if (tid == 0) { sh_cnt = 0; sh_valid = 0; sh_eqcnt = 0; }
    // float4 skey staging (2000 vector loads)
    for (int i = tid; i < NCAND / 4; i += 256) {
        float4 s4 = ((const float4*)(ws_score + base2))[i];
        skey[4 * i + 0] = ford(s4.x);
        skey[4 * i + 1] = ford(s4.y);
        skey[4 * i + 2] = ford(s4.z);
        skey[4 * i + 3] = ford(s4.w);
    }
    for (int i = tid; i < 512; i += 256) list[i] = 0;
    for (int i = tid; i < 1024; i += 256) hist4[i] = 0;
    __syncthreads();

    u64 prefix = 0;
    u32 need = K_TOT;
    const int rounds[6] = {7, 6, 5, 4, 1, 0};
    const int slot = tid & 3;

    // ---- rounds d=7, d=6: full 8000-scans (4-deep batched) ----
    for (int rd = 0; rd < 2; ++rd) {
        const int d = rounds[rd];
        for (int i0 = 0; i0 < NCAND; i0 += 1024) {
            u32 kv[4];
            #pragma unroll
            for (int q = 0; q < 4; ++q) {
                int i = i0 + tid + q * 256;
                kv[q] = (i < NCAND) ? skey[i] : 0u;
            }
            #pragma unroll
            for (int q = 0; q < 4; ++q) {
                int i = i0 + tid + q * 256;
                if (i < NCAND) {
                    u64 k = ((u64)kv[q] << 32) | (u32)(M_SEL - 1 - i);
                    bool match = (d == 7) || (((k ^ prefix) >> (8 * (d + 1))) == 0);
                    if (match)
                        atomicAdd(&hist4[(((u32)(k >> (8 * d)) & 0xFFu) << 2) | slot], 1u);
                }
            }
        }
        __syncthreads();
        if (tid < 64) {
            const int l = tid;
            u32 h[4];
            #pragma unroll
            for (int q = 0; q < 4; ++q) {
                int bin = 4 * l + q;
                h[q] = hist4[bin * 4 + 0] + hist4[bin * 4 + 1]
                     + hist4[bin * 4 + 2] + hist4[bin * 4 + 3];
                hist4[bin * 4 + 0] = 0; hist4[bin * 4 + 1] = 0;
                hist4[bin * 4 + 2] = 0; hist4[bin * 4 + 3] = 0;
            }
            u32 s3 = h[3], s2 = h[2] + s3, s1 = h[1] + s2, s0 = h[0] + s1;
            u32 tot = s0, S = tot;
            #pragma unroll
            for (int off = 1; off < 64; off <<= 1) {
                u32 t = __shfl(S, (l + off) & 63);
                if (l + off < 64) S += t;
            }
            u32 T = S - tot;
            u32 sv0 = s0 + T, sv1 = s1 + T, sv2 = s2 + T, sv3 = s3 + T;
            if (sv0 >= need && sv1 < need) { sh_sel = 4*l;     sh_need = need - sv1; }
            if (sv1 >= need && sv2 < need) { sh_sel = 4*l + 1; sh_need = need - sv2; }
            if (sv2 >= need && sv3 < need) { sh_sel = 4*l + 2; sh_need = need - sv3; }
            if (sv3 >= need && T   < need) { sh_sel = 4*l + 3; sh_need = need - T;   }
        }
        __syncthreads();
        prefix |= ((u64)(u32)sh_sel) << (8 * d);
        need = sh_need;
        __syncthreads();
    }

    // ---- compaction pass: above-prefix16 -> list (members), equal -> eq ----
    {
        const u32 p16 = (u32)(prefix >> 48);
        for (int i0 = 0; i0 < NCAND; i0 += 1024) {
            u32 kv[4];
            #pragma unroll
            for (int q = 0; q < 4; ++q) {
                int i = i0 + tid + q * 256;
                kv[q] = (i < NCAND) ? skey[i] : 0u;
            }
            #pragma unroll
            for (int q = 0; q < 4; ++q) {
                int i = i0 + tid + q * 256;
                if (i < NCAND) {
                    u64 k = ((u64)kv[q] << 32) | (u32)(M_SEL - 1 - i);
                    u32 t16 = (u32)(k >> 48);
                    if (t16 > p16) {
                        int p = atomicAdd(&sh_cnt, 1);      // <= 299 guaranteed
                        if (p < 512) list[p] = k;
                    } else if (t16 == p16) {
                        int p = atomicAdd(&sh_eqcnt, 1);
                        if (p < EQCAP) eq[p] = (u32)i;
                    }
                }
            }
        }
    }
    __syncthreads();
    const int eqn_raw = sh_eqcnt;
    const bool over = eqn_raw > EQCAP;      // tie-pathological fallback
    const int eqn = over ? 0 : eqn_raw;

    if (!over) {
        // ---- rounds d=5,4,1,0 over eq only (typ. ~25 entries) ----
        for (int rd = 2; rd < 6; ++rd) {
            const int d = rounds[rd];
            for (int j = tid; j < eqn; j += 256) {
                int i = eq[j];
                u64 k = ((u64)skey[i] << 32) | (u32)(M_SEL - 1 - i);
                bool match = (((k ^ prefix) >> (8 * (d + 1))) == 0);
                if (match)
                    atomicAdd(&hist4[(((u32)(k >> (8 * d)) & 0xFFu) << 2) | slot], 1u);
            }
            __syncthreads();
            if (tid < 64) {
                const int l = tid;
                u32 h[4];
                #pragma unroll
                for (int q = 0; q < 4; ++q) {
                    int bin = 4 * l + q;
                    h[q] = hist4[bin * 4 + 0] + hist4[bin * 4 + 1]
                         + hist4[bin * 4 + 2] + hist4[bin * 4 + 3];
                    hist4[bin * 4 + 0] = 0; hist4[bin * 4 + 1] = 0;
                    hist4[bin * 4 + 2] = 0; hist4[bin * 4 + 3] = 0;
                }
                u32 s3 = h[3], s2 = h[2] + s3, s1 = h[1] + s2, s0 = h[0] + s1;
                u32 tot = s0, S = tot;
                #pragma unroll
                for (int off = 1; off < 64; off <<= 1) {
                    u32 t = __shfl(S, (l + off) & 63);
                    if (l + off < 64) S += t;
                }
                u32 T = S - tot;
                u32 sv0 = s0 + T, sv1 = s1 + T, sv2 = s2 + T, sv3 = s3 + T;
                if (sv0 >= need && sv1 < need) { sh_sel = 4*l;     sh_need = need - sv1; }
                if (sv1 >= need && sv2 < need) { sh_sel = 4*l + 1; sh_need = need - sv2; }
                if (sv2 >= need && sv3 < need) { sh_sel = 4*l + 2; sh_need = need - sv3; }
                if (sv3 >= need && T   < need) { sh_sel = 4*l + 3; sh_need = need - T;   }
            }
            __syncthreads();
            prefix |= ((u64)(u32)sh_sel) << (8 * d);
            need = sh_need;
            __syncthreads();
        }

        // collect from eq (above-entries already in list)
        for (int j = tid; j < eqn; j += 256) {
            int i = eq[j];
            u64 k = ((u64)skey[i] << 32) | (u32)(M_SEL - 1 - i);
            if (k >= prefix) {
                int p = atomicAdd(&sh_cnt, 1);
                if (p < 512) list[p] = k;
            }
        }
    } else {
        // ---- fallback: original full-scan rounds + collect (re-zero list) ----
        __syncthreads();
        for (int i = tid; i < 512; i += 256) list[i] = 0;
        if (tid == 0) sh_cnt = 0;
        __syncthreads();
        for (int rd = 2; rd < 6; ++rd) {
            const int d = rounds[rd];
            for (int i0 = 0; i0 < NCAND; i0 += 1024) {
                u32 kv[4];
                #pragma unroll
                for (int q = 0; q < 4; ++q) {
                    int i = i0 + tid + q * 256;
                    kv[q] = (i < NCAND) ? skey[i] : 0u;
                }
                #pragma unroll
                for (int q = 0; q < 4; ++q) {
                    int i = i0 + tid + q * 256;
                    if (i < NCAND) {
                        u64 k = ((u64)kv[q] << 32) | (u32)(M_SEL - 1 - i);
                        bool match = (((k ^ prefix) >> (8 * (d + 1))) == 0);
                        if (match)
                            atomicAdd(&hist4[(((u32)(k >> (8 * d)) & 0xFFu) << 2) | slot], 1u);
                    }
                }
            }
            __syncthreads();
            if (tid < 64) {
                const int l = tid;
                u32 h[4];
                #pragma unroll
                for (int q = 0; q < 4; ++q) {
                    int bin = 4 * l + q;
                    h[q] = hist4[bin * 4 + 0] + hist4[bin * 4 + 1]
                         + hist4[bin * 4 + 2] + hist4[bin * 4 + 3];
                    hist4[bin * 4 + 0] = 0; hist4[bin * 4 + 1] = 0;
                    hist4[bin * 4 + 2] = 0; hist4[bin * 4 + 3] = 0;
                }
                u32 s3 = h[3], s2 = h[2] + s3, s1 = h[1] + s2, s0 = h[0] + s1;
                u32 tot = s0, S = tot;
                #pragma unroll
                for (int off = 1; off < 64; off <<= 1) {
                    u32 t = __shfl(S, (l + off) & 63);
                    if (l + off < 64) S += t;
                }
                u32 T = S - tot;
                u32 sv0 = s0 + T, sv1 = s1 + T, sv2 = s2 + T, sv3 = s3 + T;
                if (sv0 >= need && sv1 < need) { sh_sel = 4*l;     sh_need = need - sv1; }
                if (sv1 >= need && sv2 < need) { sh_sel = 4*l + 1; sh_need = need - sv2; }
                if (sv2 >= need && sv3 < need) { sh_sel = 4*l + 2; sh_need = need - sv3; }
                if (sv3 >= need && T   < need) { sh_sel = 4*l + 3; sh_need = need - T;   }
            }
            __syncthreads();
            prefix |= ((u64)(u32)sh_sel) << (8 * d);
            need = sh_need;
            __syncthreads();
        }
        for (int i0 = 0; i0 < NCAND; i0 += 1024) {
            u32 kv[4];
            #pragma unroll
            for (int q = 0; q < 4; ++q) {
                int i = i0 + tid + q * 256;
                kv[q] = (i < NCAND) ? skey[i] : 0u;
            }
            #pragma unroll
            for (int q = 0; q < 4; ++q) {
                int i = i0 + tid + q * 256;
                if (i < NCAND) {
                    u64 k = ((u64)kv[q] << 32) | (u32)(M_SEL - 1 - i);
                    if (k >= prefix) {
                        int p = atomicAdd(&sh_cnt, 1);
                        if (p < 512) list[p] = k;
                    }
                }
            }
        }
    }
    __syncthreads();

    // one-wave register bitonic sort of list[512], descending (pads 0 last)
    if (tid < 64) {
        const int l = tid;
        u64 e[8];
        #pragma unroll
        for (int q = 0; q < 8; ++q) e[q] = list[l * 8 + q];
        #define CE2(a, b, dd) { u64 _mx = (a) > (b) ? (a) : (b); \
                                u64 _mn = (a) > (b) ? (b) : (a); \
                                (a) = (dd) ? _mx : _mn; (b) = (dd) ? _mn : _mx; }
        CE2(e[0], e[1], true);  CE2(e[2], e[3], false);
        CE2(e[4], e[5], true);  CE2(e[6], e[7], false);
        CE2(e[0], e[2], true);  CE2(e[1], e[3], true);
        CE2(e[4], e[6], false); CE2(e[5], e[7], false);
        CE2(e[0], e[1], true);  CE2(e[2], e[3], true);
        CE2(e[4], e[5], false); CE2(e[6], e[7], false);
        for (int k = 8; k <= 512; k <<= 1) {
            const bool d = ((l & (k >> 3)) == 0);
            for (int j = k >> 1; j >= 8; j >>= 1) {
                const int dl = j >> 3;
                const bool upper = (l & dl) != 0;
                #pragma unroll
                for (int q = 0; q < 8; ++q) {
                    u64 pv = __shfl_xor(e[q], dl);
                    u64 mx = e[q] > pv ? e[q] : pv;
                    u64 mn = e[q] > pv ? pv : e[q];
                    e[q] = (d != upper) ? mx : mn;
                }
            }
            CE2(e[0], e[4], d); CE2(e[1], e[5], d);
            CE2(e[2], e[6], d); CE2(e[3], e[7], d);
            CE2(e[0], e[2], d); CE2(e[1], e[3], d);
            CE2(e[4], e[6], d); CE2(e[5], e[7], d);
            CE2(e[0], e[1], d); CE2(e[2], e[3], d);
            CE2(e[4], e[5], d); CE2(e[6], e[7], d);
        }
        #undef CE2
        #pragma unroll
        for (int q = 0; q < 8; ++q) list[l * 8 + q] = e[q];
    }
    __syncthreads();

    float* out_s = out;                         // [B,300]
    float* out_b = out + B_IMG * K_TOT;         // [B,300,4]
    float* out_c = out + B_IMG * K_TOT * 5;     // [B,300]
    float* out_n = out + B_IMG * K_TOT * 6;     // [B]

    for (int i = tid; i < K_TOT; i += 256) {
        u64 k = list[i];
        float s = funord((u32)(k >> 32));
        int flat = (M_SEL - 1) - (int)(u32)(k & 0xFFFFFFFFu);
        bool valid = s > (-5e29f);              // top_s > NEG/2
        float os = 0.0f, oc = 0.0f;
        float4 obv = make_float4(0.0f, 0.0f, 0.0f, 0.0f);
        if (valid && flat < NCAND) {
            int cc = flat / K_PER;
            int n  = ws_idx[base2 + flat];
            float4 bb = ((const float4*)boxes)[b * N_BOX + n];
            os = s;
            oc = (float)cc;
            obv.x = fminf(fmaxf(bb.x, 0.0f), 1.0f);
            obv.y = fminf(fmaxf(bb.y, 0.0f), 1.0f);
            obv.z = fminf(fmaxf(bb.z, 0.0f), 1.0f);
            obv.w = fminf(fmaxf(bb.w, 0.0f), 1.0f);
            atomicAdd(&sh_valid, 1);
        }
        out_s[b * K_TOT + i] = os;
        ((float4*)out_b)[b * K_TOT + i] = obv;
        out_c[b * K_TOT + i] = oc;
    }
    __syncthreads();
    if (tid == 0) out_n[b] = (float)sh_valid;
}

extern "C" void kernel_launch(void* const* d_in, const int* in_sizes, int n_in,
                              void* d_out, int out_size, void* d_ws, size_t ws_size,
                              hipStream_t stream) {
    const float* scores = (const float*)d_in[0];   // [4,1024,80]
    const float* boxes  = (const float*)d_in[1];   // [4,1024,1,4]

    char* ws = (char*)d_ws;                        // footprint unchanged
    int*   done_cnt = (int*)(ws + OFF_DONE);
    float* ws_score = (float*)(ws + OFF_WSCORE);
    int*   ws_idx   = (int*)  (ws + OFF_WSIDX);

    hipMemsetAsync(done_cnt, 0, B_IMG * sizeof(int), stream);
    nms_classes<<<dim3(B_IMG * C_CLS), dim3(256), 0, stream>>>(
        scores, boxes, ws_score, ws_idx, (float*)d_out, done_cnt);
}

// Round 8
// 110.585 us; speedup vs baseline: 1.1510x; 1.0860x over previous
//
#include <hip/hip_runtime.h>
#include <stdint.h>

#define N_BOX 1024
#define C_CLS 80
#define B_IMG 4
#define K_PER 100
#define K_TOT 300
#define NEGF  (-1e30f)
#define NCAND (C_CLS * K_PER)    // 8000 candidates per image
#define M_SEL 8192               // flat-index packing base for final top-k
#define KPAD  1088               // 1024 + 64 swizzle pad
#define EQCAP 768                // compacted equal-prefix16 candidate cap

// workspace layout (bytes) — proven offsets
#define OFF_WSCORE  1835008     // [B*C][K_PER] f32         128,000
#define OFF_WSIDX   1963008     // [B*C][K_PER] i32         128,000

typedef unsigned long long u64;
typedef unsigned int u32;

// LDS bank swizzle for u64 key array: bank16 rotates per 16-element group.
__device__ __forceinline__ int swz(int i) { return i + (i >> 4); }

// ---- monotone float <-> ordered-uint mapping (total order, bit-exact) ----
__device__ __forceinline__ u32 ford(float f) {
    u32 u = __float_as_uint(f);
    return (u & 0x80000000u) ? ~u : (u | 0x80000000u);
}
__device__ __forceinline__ float funord(u32 o) {
    u32 u = (o & 0x80000000u) ? (o ^ 0x80000000u) : ~o;
    return __uint_as_float(u);
}

// IoU>0.5 test, bit-identical to RN(inter/uni) > 0.5 but divide-free in the
// common case (Sterbenz-exact diff + guard band; divide only in the ambiguous
// band). Proven bit-exact r19-r21 (absmax 0).
__device__ __forceinline__ bool iou_gt_fast(float4 a, float aa, float4 b, float ab) {
#pragma clang fp contract(off)
    float ih = fminf(a.z, b.z) - fmaxf(a.x, b.x); ih = fmaxf(ih, 0.0f);
    float iw = fminf(a.w, b.w) - fmaxf(a.y, b.y); iw = fmaxf(iw, 0.0f);
    float inter = ih * iw;
    float uni = fmaxf(aa + ab - inter, 1e-12f);
    float diff = 2.0f * inter - uni;
    bool kill = diff > uni * 2.4e-7f;
    if (__builtin_expect(!kill && diff > 0.0f, 0))
        kill = (inter / uni) > 0.5f;
    return kill;
}

// ---------------------------------------------------------------------------
// Kernel 1 (r22 = r21's proven nms phase, standalone): one block per
// (image, class), 256 thr, 4 waves. Two-kernel chain restored (fusion's
// election/fence tail measured costlier than the launch gap it removed).
// ---------------------------------------------------------------------------
__global__ __launch_bounds__(256, 2) void nms_classes(
        const float* __restrict__ scores,   // [B, N, C]
        const float* __restrict__ boxes,    // [B, N, 1, 4]
        float* __restrict__ ws_score,       // [B*C*K_PER]
        int*   __restrict__ ws_idx)         // [B*C*K_PER]
{
    __shared__ u64    key[KPAD];            // 8704 B (swizzled)
    __shared__ float4 bx[N_BOX];            // 16384
    __shared__ float  ar[N_BOX];            // 4096
    __shared__ float4 wbuf[2][64];          // 2048
    __shared__ float  wab[2][64];           // 512
    __shared__ float4 kb[128];              // 2048 (padded for batch-8)
    __shared__ float  ka[128];              // 512
    __shared__ int    kept_t[K_PER];
    __shared__ u32    colk16[4][64];        // per-grp 16-bit kill rows
    __shared__ u64    sup64[4];             // per-wave suppressed ballots
    __shared__ int    sh_nvalid, sh_kept;

    const int tid  = threadIdx.x;
    const int lane = tid & 63;
    const int b  = blockIdx.x / C_CLS;
    const int c  = blockIdx.x % C_CLS;

    if (tid == 0) { sh_nvalid = 0; sh_kept = 0; }

    // ---- canonical boxes + areas into LDS ----
    for (int n = tid; n < N_BOX; n += 256) {
        float4 v = ((const float4*)boxes)[b * N_BOX + n];
        {
#pragma clang fp contract(off)
            float y1 = fminf(v.x, v.z), y2 = fmaxf(v.x, v.z);
            float x1 = fminf(v.y, v.w), x2 = fmaxf(v.y, v.w);
            bx[n] = make_float4(y1, x1, y2, x2);
            ar[n] = (y2 - y1) * (x2 - x1);
        }
    }
    __syncthreads();

    // ---- load scores: strided scalar reads (L2/L3-resident) ----
    u64 r[4];
    {
        const float* sc = scores + (size_t)(b * N_BOX) * C_CLS + c;
        int lv = 0;
        #pragma unroll
        for (int q = 0; q < 4; ++q) {
            int v = tid * 4 + q;
            float s0 = sc[(size_t)v * C_CLS];
            bool valid = s0 > 0.001f;                  // SCORE_THR
            float s = valid ? s0 : NEGF;
            r[q] = ((u64)ford(s) << 32) | (u32)(N_BOX - 1 - v);  // stable ties
            lv += valid ? 1 : 0;
        }
        if (lv) atomicAdd(&sh_nvalid, lv);
    }

    // ---- register/shuffle bitonic sort, descending (proven network) ----
    #define CE(a, b, d) { u64 _mx = (a) > (b) ? (a) : (b); \
                          u64 _mn = (a) > (b) ? (b) : (a); \
                          (a) = (d) ? _mx : _mn; (b) = (d) ? _mn : _mx; }
    CE(r[0], r[1], true); CE(r[2], r[3], false);

    for (int k = 4; k <= N_BOX; k <<= 1) {
        const bool d = ((tid & (k >> 2)) == 0);
        for (int j = k >> 1; j > 0; j >>= 1) {
            if (j >= 256) {                          // cross-wave: LDS stage
                __syncthreads();
                #pragma unroll
                for (int q = 0; q < 4; ++q) key[swz(tid * 4 + q)] = r[q];
                __syncthreads();
                const bool upper = ((tid * 4) & j) != 0;
                #pragma unroll
                for (int q = 0; q < 4; ++q) {
                    u64 pv = key[swz((tid * 4 + q) ^ j)];
                    u64 mx = r[q] > pv ? r[q] : pv;
                    u64 mn = r[q] > pv ? pv : r[q];
                    r[q] = (d != upper) ? mx : mn;
                }
            } else if (j >= 4) {                     // intra-wave: shuffle
                const int dl = j >> 2;
                const bool upper = (lane & dl) != 0;
                #pragma unroll
                for (int q = 0; q < 4; ++q) {
                    u64 pv = __shfl_xor(r[q], dl);
                    u64 mx = r[q] > pv ? r[q] : pv;
                    u64 mn = r[q] > pv ? pv : r[q];
                    r[q] = (d != upper) ? mx : mn;
                }
            } else if (j == 2) {
                CE(r[0], r[2], d); CE(r[1], r[3], d);
            } else {
                CE(r[0], r[1], d); CE(r[2], r[3], d);
            }
        }
    }
    #undef CE

    __syncthreads();
    #pragma unroll
    for (int q = 0; q < 4; ++q) key[swz(tid * 4 + q)] = r[q];
    __syncthreads();

    // ---- prologue: stage window 0's boxes (wave 0) ----
    if (tid < 64) {
        u64 kv = key[swz(tid)];
        int idx = (N_BOX - 1) - (int)(u32)(kv & 0xFFFFFFFFu);
        wbuf[0][tid] = bx[idx];
        wab[0][tid]  = ar[idx];
    }

    const int nvalid = sh_nvalid;
    const int nwin = (nvalid + 63) >> 6;
    const int me  = tid & 63;               // candidate slot in window
    const int grp = tid >> 6;               // wave id 0..3

    for (int w = 0; w < nwin; ++w) {
        const int cur = w & 1;
        __syncthreads();                    // (A) staged boxes + kept stable
        if (sh_kept >= K_PER) break;        // wave-uniform
        const int kept0 = sh_kept;
        const int bt = w * 64;

        // stage NEXT window (wave 1) — chain hides under IoU VALU
        if (grp == 1 && (w + 1) < nwin) {
            u64 kv = key[swz((bt + 64 + me) & (N_BOX - 1))];
            int idx = (N_BOX - 1) - (int)(u32)(kv & 0xFFFFFFFFu);
            wbuf[cur ^ 1][me] = bx[idx];
            wab[cur ^ 1][me]  = ar[idx];
        }

        // my candidate
        const float4 qm = wbuf[cur][me];
        const float  am = wab[cur][me];

        // intra-window kill rows grp*16..+15: batch-load then compute
        {
            float4 wrow[16]; float warow[16];
            #pragma unroll
            for (int rq = 0; rq < 16; ++rq) {
                wrow[rq]  = wbuf[cur][grp * 16 + rq];
                warow[rq] = wab[cur][grp * 16 + rq];
            }
            u32 bits = 0;
            #pragma unroll
            for (int rq = 0; rq < 16; ++rq) {
                int rr = grp * 16 + rq;
                bool kill = (rr != me) && iou_gt_fast(wrow[rq], warow[rq], qm, am);
                bits |= ((u32)kill) << rq;
            }
            colk16[grp][me] = bits;                   // unique writer
        }

        // cross-window vs kept list: strided over waves, batch-8 loads
        {
            bool supme = false;
            for (int t0 = 0; grp + 4 * t0 < kept0; t0 += 8) {
                float4 kbl[8]; float kal[8];
                #pragma unroll
                for (int i = 0; i < 8; ++i) {
                    int k = grp + 4 * (t0 + i);       // <= 127, padded
                    kbl[i] = kb[k]; kal[i] = ka[k];
                }
                #pragma unroll
                for (int i = 0; i < 8; ++i) {
                    int k = grp + 4 * (t0 + i);
                    if (k < kept0 && iou_gt_fast(kbl[i], kal[i], qm, am)) supme = true;
                }
            }
            u64 bal = __ballot(supme);
            if (lane == 0) sup64[grp] = bal;
        }
        __syncthreads();                    // (C) masks ready

        // greedy accept loop: wave 0 only, slim bit-ops body
        if (grp == 0) {
            u32 c0 = colk16[0][lane], c1 = colk16[1][lane];
            u32 c2 = colk16[2][lane], c3 = colk16[3][lane];
            u64 colkill = (u64)c0 | ((u64)c1 << 16)
                        | ((u64)c2 << 32) | ((u64)c3 << 48);
            u64 supp = sup64[0] | sup64[1] | sup64[2] | sup64[3];
            bool in = ((bt + lane) < nvalid) && !((supp >> lane) & 1ull);
            u64 pending = __ballot(in);
            int kept = kept0;
            u64 acc = 0;
            while (pending && kept < K_PER) {
                int t0 = __ffsll((long long)pending) - 1;   // wave-uniform
                acc |= 1ull << t0;
                kept++;
                bool kill = (colkill >> t0) & 1ull;
                pending &= ~(1ull << t0);
                pending &= ~__ballot(kill);
            }
            // batched commit: ffs order == ascending lane, so popcount ranks
            if ((acc >> lane) & 1ull) {
                int pos = kept0 + (int)__popcll(acc & ((1ull << lane) - 1ull));
                kept_t[pos] = bt + lane;
                kb[pos] = qm; ka[pos] = am;
            }
            if (lane == 0) sh_kept = kept;
        }
    }
    __syncthreads();

    const int kept = sh_kept;
    if (tid < K_PER) {
        int ob = (b * C_CLS + c) * K_PER + tid;
        if (tid < kept) {
            u64 k = key[swz(kept_t[tid])];
            ws_score[ob] = funord((u32)(k >> 32));
            ws_idx[ob]   = (N_BOX - 1) - (int)(u32)(k & 0xFFFFFFFFu);
        } else {
            ws_score[ob] = NEGF;
            ws_idx[ob]   = 0;
        }
    }
}

// ---------------------------------------------------------------------------
// Kernel 2 (r22): final top-300, 1024 thr, with r21-proven eq-compaction:
// passes d=7,6 full; compaction appends >prefix16 keys to list (guaranteed
// members) and gathers ==prefix16 indices into eq[768]; rounds {5,4,1,0} +
// collect scan eq only. Overflow falls back to full scans. Bit-exact (r21).
// ---------------------------------------------------------------------------
__global__ __launch_bounds__(1024) void final_topk(
        const float* __restrict__ ws_score,
        const int*   __restrict__ ws_idx,
        const float* __restrict__ boxes,    // [B, N, 1, 4]
        float* __restrict__ out)
{
    __shared__ u32 skey[NCAND];             // 32000
    __shared__ u32 hist4[1024];             // 4096
    __shared__ u64 list[512];               // 4096
    __shared__ u32 eq[EQCAP];               // 3072
    __shared__ int sh_sel, sh_cnt, sh_valid, sh_eqcnt;
    __shared__ u32 sh_need;

    const int tid = threadIdx.x;
    const int b = blockIdx.x;
    const int base = b * NCAND;

    if (tid == 0) { sh_cnt = 0; sh_valid = 0; sh_eqcnt = 0; }
    // float4 skey staging
    for (int i = tid; i < NCAND / 4; i += 1024) {
        float4 s4 = ((const float4*)(ws_score + base))[i];
        skey[4 * i + 0] = ford(s4.x);
        skey[4 * i + 1] = ford(s4.y);
        skey[4 * i + 2] = ford(s4.z);
        skey[4 * i + 3] = ford(s4.w);
    }
    if (tid < 512) list[tid] = 0;
    hist4[tid] = 0;
    __syncthreads();

    u64 prefix = 0;
    u32 need = K_TOT;
    const int rounds[6] = {7, 6, 5, 4, 1, 0};
    const int slot = tid & 3;

    // ---- rounds d=7, d=6: full scans, 4-deep batched ----
    for (int rd = 0; rd < 2; ++rd) {
        const int d = rounds[rd];
        for (int i0 = 0; i0 < NCAND; i0 += 4096) {
            u32 kv[4];
            #pragma unroll
            for (int q = 0; q < 4; ++q) {
                int i = i0 + tid + q * 1024;
                kv[q] = (i < NCAND) ? skey[i] : 0u;
            }
            #pragma unroll
            for (int q = 0; q < 4; ++q) {
                int i = i0 + tid + q * 1024;
                if (i < NCAND) {
                    u64 k = ((u64)kv[q] << 32) | (u32)(M_SEL - 1 - i);
                    // d==7 guard: shift by 64 is UB (short-circuit protects)
                    bool match = (d == 7) || (((k ^ prefix) >> (8 * (d + 1))) == 0);
                    if (match)
                        atomicAdd(&hist4[(((u32)(k >> (8 * d)) & 0xFFu) << 2) | slot], 1u);
                }
            }
        }
        __syncthreads();
        if (tid < 64) {
            const int l = tid;
            u32 h[4];
            #pragma unroll
            for (int q = 0; q < 4; ++q) {
                int bin = 4 * l + q;
                h[q] = hist4[bin * 4 + 0] + hist4[bin * 4 + 1]
                     + hist4[bin * 4 + 2] + hist4[bin * 4 + 3];
                hist4[bin * 4 + 0] = 0; hist4[bin * 4 + 1] = 0;
                hist4[bin * 4 + 2] = 0; hist4[bin * 4 + 3] = 0;
            }
            u32 s3 = h[3], s2 = h[2] + s3, s1 = h[1] + s2, s0 = h[0] + s1;
            u32 tot = s0, S = tot;
            #pragma unroll
            for (int off = 1; off < 64; off <<= 1) {
                u32 t = __shfl(S, (l + off) & 63);
                if (l + off < 64) S += t;
            }
            u32 T = S - tot;
            u32 sv0 = s0 + T, sv1 = s1 + T, sv2 = s2 + T, sv3 = s3 + T;
            if (sv0 >= need && sv1 < need) { sh_sel = 4*l;     sh_need = need - sv1; }
            if (sv1 >= need && sv2 < need) { sh_sel = 4*l + 1; sh_need = need - sv2; }
            if (sv2 >= need && sv3 < need) { sh_sel = 4*l + 2; sh_need = need - sv3; }
            if (sv3 >= need && T   < need) { sh_sel = 4*l + 3; sh_need = need - T;   }
        }
        __syncthreads();
        prefix |= ((u64)(u32)sh_sel) << (8 * d);
        need = sh_need;
        __syncthreads();
    }

    // ---- compaction: above-prefix16 -> list (members), equal -> eq ----
    {
        const u32 p16 = (u32)(prefix >> 48);
        for (int i0 = 0; i0 < NCAND; i0 += 4096) {
            u32 kv[4];
            #pragma unroll
            for (int q = 0; q < 4; ++q) {
                int i = i0 + tid + q * 1024;
                kv[q] = (i < NCAND) ? skey[i] : 0u;
            }
            #pragma unroll
            for (int q = 0; q < 4; ++q) {
                int i = i0 + tid + q * 1024;
                if (i < NCAND) {
                    u64 k = ((u64)kv[q] << 32) | (u32)(M_SEL - 1 - i);
                    u32 t16 = (u32)(k >> 48);
                    if (t16 > (u32)(prefix >> 48)) {
                        int p = atomicAdd(&sh_cnt, 1);      // <= 299 guaranteed
                        if (p < 512) list[p] = k;
                    } else if (t16 == p16) {
                        int p = atomicAdd(&sh_eqcnt, 1);
                        if (p < EQCAP) eq[p] = (u32)i;
                    }
                }
            }
        }
    }
    __syncthreads();
    const int eqn_raw = sh_eqcnt;
    const bool over = eqn_raw > EQCAP;      // tie-pathological fallback
    const int eqn = over ? 0 : eqn_raw;

    if (!over) {
        // ---- rounds d=5,4,1,0 over eq only ----
        for (int rd = 2; rd < 6; ++rd) {
            const int d = rounds[rd];
            for (int j = tid; j < eqn; j += 1024) {
                int i = eq[j];
                u64 k = ((u64)skey[i] << 32) | (u32)(M_SEL - 1 - i);
                bool match = (((k ^ prefix) >> (8 * (d + 1))) == 0);
                if (match)
                    atomicAdd(&hist4[(((u32)(k >> (8 * d)) & 0xFFu) << 2) | slot], 1u);
            }
            __syncthreads();
            if (tid < 64) {
                const int l = tid;
                u32 h[4];
                #pragma unroll
                for (int q = 0; q < 4; ++q) {
                    int bin = 4 * l + q;
                    h[q] = hist4[bin * 4 + 0] + hist4[bin * 4 + 1]
                         + hist4[bin * 4 + 2] + hist4[bin * 4 + 3];
                    hist4[bin * 4 + 0] = 0; hist4[bin * 4 + 1] = 0;
                    hist4[bin * 4 + 2] = 0; hist4[bin * 4 + 3] = 0;
                }
                u32 s3 = h[3], s2 = h[2] + s3, s1 = h[1] + s2, s0 = h[0] + s1;
                u32 tot = s0, S = tot;
                #pragma unroll
                for (int off = 1; off < 64; off <<= 1) {
                    u32 t = __shfl(S, (l + off) & 63);
                    if (l + off < 64) S += t;
                }
                u32 T = S - tot;
                u32 sv0 = s0 + T, sv1 = s1 + T, sv2 = s2 + T, sv3 = s3 + T;
                if (sv0 >= need && sv1 < need) { sh_sel = 4*l;     sh_need = need - sv1; }
                if (sv1 >= need && sv2 < need) { sh_sel = 4*l + 1; sh_need = need - sv2; }
                if (sv2 >= need && sv3 < need) { sh_sel = 4*l + 2; sh_need = need - sv3; }
                if (sv3 >= need && T   < need) { sh_sel = 4*l + 3; sh_need = need - T;   }
            }
            __syncthreads();
            prefix |= ((u64)(u32)sh_sel) << (8 * d);
            need = sh_need;
            __syncthreads();
        }

        // collect from eq (above-entries already in list)
        for (int j = tid; j < eqn; j += 1024) {
            int i = eq[j];
            u64 k = ((u64)skey[i] << 32) | (u32)(M_SEL - 1 - i);
            if (k >= prefix) {
                int p = atomicAdd(&sh_cnt, 1);
                if (p < 512) list[p] = k;
            }
        }
    } else {
        // ---- fallback: full-scan rounds + collect (re-zero list) ----
        __syncthreads();
        if (tid < 512) list[tid] = 0;
        if (tid == 0) sh_cnt = 0;
        __syncthreads();
        for (int rd = 2; rd < 6; ++rd) {
            const int d = rounds[rd];
            for (int i0 = 0; i0 < NCAND; i0 += 4096) {
                u32 kv[4];
                #pragma unroll
                for (int q = 0; q < 4; ++q) {
                    int i = i0 + tid + q * 1024;
                    kv[q] = (i < NCAND) ? skey[i] : 0u;
                }
                #pragma unroll
                for (int q = 0; q < 4; ++q) {
                    int i = i0 + tid + q * 1024;
                    if (i < NCAND) {
                        u64 k = ((u64)kv[q] << 32) | (u32)(M_SEL - 1 - i);
                        bool match = (((k ^ prefix) >> (8 * (d + 1))) == 0);
                        if (match)
                            atomicAdd(&hist4[(((u32)(k >> (8 * d)) & 0xFFu) << 2) | slot], 1u);
                    }
                }
            }
            __syncthreads();
            if (tid < 64) {
                const int l = tid;
                u32 h[4];
                #pragma unroll
                for (int q = 0; q < 4; ++q) {
                    int bin = 4 * l + q;
                    h[q] = hist4[bin * 4 + 0] + hist4[bin * 4 + 1]
                         + hist4[bin * 4 + 2] + hist4[bin * 4 + 3];
                    hist4[bin * 4 + 0] = 0; hist4[bin * 4 + 1] = 0;
                    hist4[bin * 4 + 2] = 0; hist4[bin * 4 + 3] = 0;
                }
                u32 s3 = h[3], s2 = h[2] + s3, s1 = h[1] + s2, s0 = h[0] + s1;
                u32 tot = s0, S = tot;
                #pragma unroll
                for (int off = 1; off < 64; off <<= 1) {
                    u32 t = __shfl(S, (l + off) & 63);
                    if (l + off < 64) S += t;
                }
                u32 T = S - tot;
                u32 sv0 = s0 + T, sv1 = s1 + T, sv2 = s2 + T, sv3 = s3 + T;
                if (sv0 >= need && sv1 < need) { sh_sel = 4*l;     sh_need = need - sv1; }
                if (sv1 >= need && sv2 < need) { sh_sel = 4*l + 1; sh_need = need - sv2; }
                if (sv2 >= need && sv3 < need) { sh_sel = 4*l + 2; sh_need = need - sv3; }
                if (sv3 >= need && T   < need) { sh_sel = 4*l + 3; sh_need = need - T;   }
            }
            __syncthreads();
            prefix |= ((u64)(u32)sh_sel) << (8 * d);
            need = sh_need;
            __syncthreads();
        }
        for (int i0 = 0; i0 < NCAND; i0 += 4096) {
            u32 kv[4];
            #pragma unroll
            for (int q = 0; q < 4; ++q) {
                int i = i0 + tid + q * 1024;
                kv[q] = (i < NCAND) ? skey[i] : 0u;
            }
            #pragma unroll
            for (int q = 0; q < 4; ++q) {
                int i = i0 + tid + q * 1024;
                if (i < NCAND) {
                    u64 k = ((u64)kv[q] << 32) | (u32)(M_SEL - 1 - i);
                    if (k >= prefix) {
                        int p = atomicAdd(&sh_cnt, 1);
                        if (p < 512) list[p] = k;
                    }
                }
            }
        }
    }
    __syncthreads();

    // one-wave register bitonic sort of list[512], descending (pads 0 last)
    if (tid < 64) {
        const int l = tid;
        u64 e[8];
        #pragma unroll
        for (int q = 0; q < 8; ++q) e[q] = list[l * 8 + q];
        #define CE2(a, b, dd) { u64 _mx = (a) > (b) ? (a) : (b); \
                                u64 _mn = (a) > (b) ? (b) : (a); \
                                (a) = (dd) ? _mx : _mn; (b) = (dd) ? _mn : _mx; }
        CE2(e[0], e[1], true);  CE2(e[2], e[3], false);
        CE2(e[4], e[5], true);  CE2(e[6], e[7], false);
        CE2(e[0], e[2], true);  CE2(e[1], e[3], true);
        CE2(e[4], e[6], false); CE2(e[5], e[7], false);
        CE2(e[0], e[1], true);  CE2(e[2], e[3], true);
        CE2(e[4], e[5], false); CE2(e[6], e[7], false);
        for (int k = 8; k <= 512; k <<= 1) {
            const bool d = ((l & (k >> 3)) == 0);
            for (int j = k >> 1; j >= 8; j >>= 1) {
                const int dl = j >> 3;
                const bool upper = (l & dl) != 0;
                #pragma unroll
                for (int q = 0; q < 8; ++q) {
                    u64 pv = __shfl_xor(e[q], dl);
                    u64 mx = e[q] > pv ? e[q] : pv;
                    u64 mn = e[q] > pv ? pv : e[q];
                    e[q] = (d != upper) ? mx : mn;
                }
            }
            CE2(e[0], e[4], d); CE2(e[1], e[5], d);
            CE2(e[2], e[6], d); CE2(e[3], e[7], d);
            CE2(e[0], e[2], d); CE2(e[1], e[3], d);
            CE2(e[4], e[6], d); CE2(e[5], e[7], d);
            CE2(e[0], e[1], d); CE2(e[2], e[3], d);
            CE2(e[4], e[5], d); CE2(e[6], e[7], d);
        }
        #undef CE2
        #pragma unroll
        for (int q = 0; q < 8; ++q) list[l * 8 + q] = e[q];
    }
    __syncthreads();

    float* out_s = out;                         // [B,300]
    float* out_b = out + B_IMG * K_TOT;         // [B,300,4]
    float* out_c = out + B_IMG * K_TOT * 5;     // [B,300]
    float* out_n = out + B_IMG * K_TOT * 6;     // [B]

    for (int i = tid; i < K_TOT; i += 1024) {
        u64 k = list[i];
        float s = funord((u32)(k >> 32));
        int flat = (M_SEL - 1) - (int)(u32)(k & 0xFFFFFFFFu);
        bool valid = s > (-5e29f);              // top_s > NEG/2
        float os = 0.0f, oc = 0.0f;
        float4 obv = make_float4(0.0f, 0.0f, 0.0f, 0.0f);
        if (valid && flat < NCAND) {
            int cc = flat / K_PER;
            int n  = ws_idx[base + flat];
            float4 bb = ((const float4*)boxes)[b * N_BOX + n];
            os = s;
            oc = (float)cc;
            obv.x = fminf(fmaxf(bb.x, 0.0f), 1.0f);
            obv.y = fminf(fmaxf(bb.y, 0.0f), 1.0f);
            obv.z = fminf(fmaxf(bb.z, 0.0f), 1.0f);
            obv.w = fminf(fmaxf(bb.w, 0.0f), 1.0f);
            atomicAdd(&sh_valid, 1);
        }
        out_s[b * K_TOT + i] = os;
        ((float4*)out_b)[b * K_TOT + i] = obv;
        out_c[b * K_TOT + i] = oc;
    }
    __syncthreads();
    if (tid == 0) out_n[b] = (float)sh_valid;
}

extern "C" void kernel_launch(void* const* d_in, const int* in_sizes, int n_in,
                              void* d_out, int out_size, void* d_ws, size_t ws_size,
                              hipStream_t stream) {
    const float* scores = (const float*)d_in[0];   // [4,1024,80]
    const float* boxes  = (const float*)d_in[1];   // [4,1024,1,4]

    char* ws = (char*)d_ws;                        // footprint unchanged
    float* ws_score = (float*)(ws + OFF_WSCORE);
    int*   ws_idx   = (int*)  (ws + OFF_WSIDX);

    nms_classes<<<dim3(B_IMG * C_CLS), dim3(256), 0, stream>>>(
        scores, boxes, ws_score, ws_idx);
    final_topk<<<dim3(B_IMG), dim3(1024), 0, stream>>>(
        ws_score, ws_idx, boxes, (float*)d_out);
}